// Round 6
// baseline (652.365 us; speedup 1.0000x reference)
//
#include <hip/hip_runtime.h>

// Problem constants (B=2, C=32, E=128, S=64, K=7, pad=3). All float32 I/O.
#define S 64
#define S2 4096
#define S3 262144
#define NVOX (2 * S3)     // B * S^3 total voxels
#define C 32
#define E 128
#define LN_EPS 1e-6f

// conv tile: D=8, H=8, W=64. 256 threads = 8 wq x 4 hg x 8 dd.
// Each thread: 8 W x 2 consecutive H outputs -> one row read serves two kh's.
// Halo: 14 D-slabs x 14 H-rows x 70 dwords, one 80-dword slot per row:
//   base(Dk,m) = 80*(14*Dk+m) + pad,  pad = 4*(Dk&1) + ((m>>1)&3)  (in [0,7])
// 70+pad <= 77 < 80  -> rows can NEVER overlap (round-5 bug fixed).
// base mod 8 = pad. In-flight rows per ds_read: 2 consecutive Dk (even+odd
// -> {0,4}) x m in {t,t+2,t+4,t+6} ((m>>1)&3 -> {0,1,2,3}) = all 8 mod-8
// bank classes exactly once -> 2 lanes/bank -> conflict-free (free, m136).
#define ROWSLOT 80
#define NROWS  196                 // 14 slabs x 14 rows
#define HALO_SZ (ROWSLOT * NROWS)  // 15680 dwords = 62.7 KB -> 2 blocks/CU

__global__ __launch_bounds__(256) void k_conv(
    const float* __restrict__ x,
    const int* __restrict__ mask,
    const float* __restrict__ wdw,
    const float* __restrict__ bdw,
    float* __restrict__ y)
{
    __shared__ float halo[HALO_SZ];

    const int bx = blockIdx.x;            // 64 spatial tiles: 8 (D) x 8 (H)
    const int by = blockIdx.y;            // 64: b*C + c
    const int b  = by >> 5;
    const int c  = by & 31;
    const int d0 = (bx >> 3) * 8;
    const int h0 = (bx & 7) * 8;
    const int tid = threadIdx.x;

    const float* xc = x + (size_t)(b * C + c) * S3;
    const int* mb = mask + (size_t)b * S3;

    // stage masked halo (zero-pad at volume edges); x/mask loads independent
    for (int t = tid; t < NROWS * 72; t += 256) {
        int r   = t / 72;
        int cln = t - r * 72;
        if (cln < 70) {
            int Dk = r / 14;
            int m  = r - Dk * 14;
            int gw = cln - 3;
            int gh = h0 + m - 3;
            int gd = d0 + Dk - 3;
            float v = 0.f;
            if ((unsigned)gw < 64u && (unsigned)gh < 64u && (unsigned)gd < 64u) {
                int off = gd * S2 + gh * S + gw;
                float xv = xc[off];       // independent loads, issue in parallel
                int   mv = mb[off];
                v = mv ? xv : 0.f;
            }
            int pad = (((Dk & 1) << 2)) + ((m >> 1) & 3);
            halo[ROWSLOT * r + pad + cln] = v;
        }
    }
    __syncthreads();

    const int wq = tid & 7;
    const int hg = (tid >> 3) & 3;
    const int dd = tid >> 5;
    const int w0 = wq << 3;

    float acc0[8], acc1[8];
    #pragma unroll
    for (int j = 0; j < 8; ++j) { acc0[j] = 0.f; acc1[j] = 0.f; }

    const float* wc = wdw + c * 343;

    for (int kd = 0; kd < 7; ++kd) {
        const int Dk    = dd + kd;
        const int slab  = ROWSLOT * 14 * Dk + ((Dk & 1) << 2);
        #pragma unroll
        for (int t = 0; t < 8; ++t) {
            const int m  = 2 * hg + t;
            const int rb = slab + ROWSLOT * m + ((m >> 1) & 3);
            const float* row = &halo[rb + w0];
            float in14[14];
            #pragma unroll
            for (int p = 0; p < 14; ++p) in14[p] = row[p];   // b32, 2-way max
            if (t <= 6) {                                    // h = 2hg,   kh = t
                const float* wr = wc + kd * 49 + t * 7;
                #pragma unroll
                for (int kw = 0; kw < 7; ++kw) {
                    float wt = wr[kw];
                    #pragma unroll
                    for (int j = 0; j < 8; ++j)
                        acc0[j] = fmaf(wt, in14[j + kw], acc0[j]);
                }
            }
            if (t >= 1) {                                    // h = 2hg+1, kh = t-1
                const float* wr = wc + kd * 49 + (t - 1) * 7;
                #pragma unroll
                for (int kw = 0; kw < 7; ++kw) {
                    float wt = wr[kw];
                    #pragma unroll
                    for (int j = 0; j < 8; ++j)
                        acc1[j] = fmaf(wt, in14[j + kw], acc1[j]);
                }
            }
        }
    }

    const int gd  = d0 + dd;
    const int gh0 = h0 + 2 * hg;
    const float bb = bdw[c];
    const size_t obase = (size_t)(b * C + c) * S3 + gd * S2 + gh0 * S + w0;
    const int mbase = gd * S2 + gh0 * S + w0;

    float ov[8];
    #pragma unroll
    for (int j = 0; j < 8; ++j)
        ov[j] = (mb[mbase + j] != 0) ? (acc0[j] + bb) : 0.f;
    *(float4*)(y + obase)     = make_float4(ov[0], ov[1], ov[2], ov[3]);
    *(float4*)(y + obase + 4) = make_float4(ov[4], ov[5], ov[6], ov[7]);

    #pragma unroll
    for (int j = 0; j < 8; ++j)
        ov[j] = (mb[mbase + S + j] != 0) ? (acc1[j] + bb) : 0.f;
    *(float4*)(y + obase + S)     = make_float4(ov[0], ov[1], ov[2], ov[3]);
    *(float4*)(y + obase + S + 4) = make_float4(ov[4], ov[5], ov[6], ov[7]);
}

// ---- sorted compaction over ALL NVOX voxels: count -> scan -> scatter
__global__ __launch_bounds__(256) void k_count(
    const int* __restrict__ mask, int* __restrict__ bcnt)
{
    int v = blockIdx.x * 256 + threadIdx.x;
    int act = (mask[v] != 0) ? 1 : 0;
    unsigned long long ball = __ballot(act);
    __shared__ int wsum[4];
    int lane = threadIdx.x & 63, wid = threadIdx.x >> 6;
    if (lane == 0) wsum[wid] = __popcll(ball);
    __syncthreads();
    if (threadIdx.x == 0)
        bcnt[blockIdx.x] = wsum[0] + wsum[1] + wsum[2] + wsum[3];
}

__global__ __launch_bounds__(256) void k_scan(
    const int* __restrict__ bcnt, int* __restrict__ bbase, int* __restrict__ ntot)
{
    int t = threadIdx.x;                 // 256 threads, 8 counts each (2048 blocks)
    int cv[8]; int s = 0;
    #pragma unroll
    for (int j = 0; j < 8; ++j) { cv[j] = bcnt[t * 8 + j]; s += cv[j]; }
    int lane = t & 63, wid = t >> 6;
    int x = s;                           // inclusive wave scan
    #pragma unroll
    for (int off = 1; off < 64; off <<= 1) {
        int yv = __shfl_up(x, off, 64);
        if (lane >= off) x += yv;
    }
    __shared__ int wtot[4];
    if (lane == 63) wtot[wid] = x;
    __syncthreads();
    int wbase = 0;
    for (int w = 0; w < wid; ++w) wbase += wtot[w];
    int run = wbase + x - s;             // exclusive prefix for this thread's first block
    #pragma unroll
    for (int j = 0; j < 8; ++j) { bbase[t * 8 + j] = run; run += cv[j]; }
    if (t == 255) *ntot = run;
}

__global__ __launch_bounds__(256) void k_scatter(
    const int* __restrict__ mask, const int* __restrict__ bbase,
    int* __restrict__ list)
{
    int v = blockIdx.x * 256 + threadIdx.x;
    int act = (mask[v] != 0) ? 1 : 0;
    unsigned long long ball = __ballot(act);
    int lane = threadIdx.x & 63, wid = threadIdx.x >> 6;
    __shared__ int wcnt[4];
    if (lane == 0) wcnt[wid] = __popcll(ball);
    __syncthreads();
    int base = bbase[blockIdx.x];
    for (int w = 0; w < wid; ++w) base += wcnt[w];
    int pre = __popcll(ball & ((1ull << lane) - 1ull));
    if (act) list[base + pre] = v;       // globally sorted: blocks & lanes in order
}

// Fast erf: Abramowitz-Stegun 7.1.26, |err| < 2e-6 in fp32 range.
__device__ __forceinline__ float erf_fast(float z) {
    float az = fabsf(z);
    float t = 1.f / fmaf(0.3275911f, az, 1.f);
    float p = t * fmaf(t, fmaf(t, fmaf(t, fmaf(t, 1.061405429f, -1.453152027f),
                     1.421413741f), -0.284496736f), 0.254829592f);
    float r = 1.f - p * __expf(-az * az);
    return copysignf(r, z);
}

// Per-active-voxel: LN over C, expand+GELU, project, +residual.
// y lives in d_out; each thread reads then overwrites only its own 32 slots.
__global__ __launch_bounds__(256) void k_mlp(
    const float* __restrict__ x,
    const float* __restrict__ lng,
    const float* __restrict__ lnb,
    const float* __restrict__ w2,
    const float* __restrict__ b2v,
    const float* __restrict__ w3,
    const float* __restrict__ b3v,
    const int* __restrict__ mask,
    const int* __restrict__ ntot,
    const int* __restrict__ list,
    float* __restrict__ out)
{
    int i = blockIdx.x * 256 + threadIdx.x;
    int v;
    if (list != nullptr) {
        if (i >= *ntot) return;
        v = list[i];                     // sorted -> near-coalesced gathers
    } else {
        v = i;
        if (mask[v] == 0) return;
    }
    const int b = v >> 18;
    const int s = v & (S3 - 1);
    const size_t base = (size_t)b * C * S3 + s;

    float yv[32], xr[32];
    #pragma unroll
    for (int c = 0; c < 32; ++c) yv[c] = out[base + (size_t)c * S3];
    #pragma unroll
    for (int c = 0; c < 32; ++c) xr[c] = x[base + (size_t)c * S3];  // prefetch residual

    float mu = 0.f;
    #pragma unroll
    for (int c = 0; c < 32; ++c) mu += yv[c];
    mu *= (1.f / 32.f);
    float var = 0.f;
    #pragma unroll
    for (int c = 0; c < 32; ++c) { float d = yv[c] - mu; var += d * d; }
    var *= (1.f / 32.f);
    const float rs = rsqrtf(var + LN_EPS);
    #pragma unroll
    for (int c = 0; c < 32; ++c)
        yv[c] = (yv[c] - mu) * rs * lng[c] + lnb[c];

    float o[32];
    #pragma unroll
    for (int c = 0; c < 32; ++c) o[c] = b3v[c];

    for (int e = 0; e < E; ++e) {
        float a = b2v[e];
        const float* w2r = w2 + e * 32;   // uniform -> scalar loads
        #pragma unroll
        for (int c = 0; c < 32; ++c) a = fmaf(w2r[c], yv[c], a);
        float g = 0.5f * a * (1.f + erf_fast(a * 0.70710678118654752f)); // exact GELU
        #pragma unroll
        for (int c = 0; c < 32; ++c) o[c] = fmaf(w3[c * 128 + e], g, o[c]);
    }

    #pragma unroll
    for (int c = 0; c < 32; ++c)
        out[base + (size_t)c * S3] = xr[c] + o[c];
}

extern "C" void kernel_launch(void* const* d_in, const int* in_sizes, int n_in,
                              void* d_out, int out_size, void* d_ws, size_t ws_size,
                              hipStream_t stream)
{
    const float* x   = (const float*)d_in[0];
    const int*   m   = (const int*)d_in[1];
    const float* wdw = (const float*)d_in[2];
    const float* bdw = (const float*)d_in[3];
    const float* lng = (const float*)d_in[4];
    const float* lnb = (const float*)d_in[5];
    const float* w2  = (const float*)d_in[6];
    const float* b2v = (const float*)d_in[7];
    const float* w3  = (const float*)d_in[8];
    const float* b3v = (const float*)d_in[9];
    float* out = (float*)d_out;

    // conv writes full masked y straight into d_out (inactive voxels -> 0,
    // which is also the correct final output there). No d_out memset needed.
    k_conv<<<dim3(64, 64), 256, 0, stream>>>(x, m, wdw, bdw, out);

    // ws layout: [ntot:4][pad][bcnt:8KB][bbase:8KB][list:2MB]
    const size_t need = 256 + 8192 + 8192 + (size_t)NVOX * sizeof(int);
    if (ws_size >= need) {
        int* ntot  = (int*)d_ws;
        int* bcnt  = (int*)((char*)d_ws + 256);
        int* bbase = (int*)((char*)d_ws + 256 + 8192);
        int* list  = (int*)((char*)d_ws + 256 + 16384);
        k_count  <<<2048, 256, 0, stream>>>(m, bcnt);
        k_scan   <<<1,    256, 0, stream>>>(bcnt, bbase, ntot);
        k_scatter<<<2048, 256, 0, stream>>>(m, bbase, list);
        k_mlp<<<2048, 256, 0, stream>>>(x, lng, lnb, w2, b2v, w3, b3v,
                                        m, ntot, list, out);
    } else {
        k_mlp<<<2048, 256, 0, stream>>>(x, lng, lnb, w2, b2v, w3, b3v,
                                        m, nullptr, nullptr, out);
    }
}

// Round 7
// 465.028 us; speedup vs baseline: 1.4029x; 1.4029x over previous
//
#include <hip/hip_runtime.h>

// Problem constants (B=2, C=32, E=128, S=64, K=7, pad=3). All float32 I/O.
#define S 64
#define S2 4096
#define S3 262144
#define NVOX (2 * S3)     // B * S^3 total voxels
#define C 32
#define E 128
#define LN_EPS 1e-6f

// conv tile: D=8, H=8, W=64. 256 threads = 8 wq x 4 hg x 8 dd.
// Each thread: 8 W x 2 consecutive H outputs; x staged in LDS as PACKED BF16
// (2 values/dword). Halo: 14 slabs x 14 rows x 70 values = 35 dwords/row,
// one 40-dword slot per row (40 = 8 mod 32):
//   base(Dk,m) = 40*(14*Dk+m) + ((m>>1)&3)       [35+3 <= 40: no overlap]
// Reader dword addr = base + 4*wq + p, p in [0,7). Bank mod 32 =
// 8*((2Dk+m)&3) + ((m>>1)&3) + 4*wq + p: within each 32-lane half-wave
// (fixed dd), the 4 hg values are separated mod 4 by pad and mod 32 by the
// 8*() term; 4*wq spans 8 distinct strides -> all 32 banks distinct per
// half-wave AND per 16-lane quarter. (Round-6 conflict source: wq and wq+4
// collided at 8*wq mod 32 within a phase.)
#define ROWSLOT 40
#define NROWS  196                 // 14 slabs x 14 rows
#define HALO_SZ (ROWSLOT * NROWS)  // 7840 dwords = 31.4 KB

__device__ __forceinline__ unsigned f2b_bits(float f) {
    union { float f; unsigned u; } x; x.f = f;
    unsigned r = x.u + 0x7fffu + ((x.u >> 16) & 1u);   // RNE
    return r >> 16;
}
__device__ __forceinline__ float hi2f(unsigned u) {
    union { unsigned u; float f; } x; x.u = u & 0xffff0000u; return x.f;
}
__device__ __forceinline__ float lo2f(unsigned u) {
    union { unsigned u; float f; } x; x.u = u << 16; return x.f;
}

__global__ __launch_bounds__(256) void k_conv(
    const float* __restrict__ x,
    const int* __restrict__ mask,
    const float* __restrict__ wdw,
    const float* __restrict__ bdw,
    float* __restrict__ y)
{
    __shared__ unsigned halo[HALO_SZ];

    const int bx = blockIdx.x;            // 64 spatial tiles: 8 (D) x 8 (H)
    const int by = blockIdx.y;            // 64: b*C + c
    const int b  = by >> 5;
    const int c  = by & 31;
    const int d0 = (bx >> 3) * 8;
    const int h0 = (bx & 7) * 8;
    const int tid = threadIdx.x;

    const float* xc = x + (size_t)(b * C + c) * S3;
    const int* mb = mask + (size_t)b * S3;

    // stage masked halo as packed bf16 pairs (zero-pad at volume edges)
    for (int t = tid; t < NROWS * 36; t += 256) {
        int r = t / 36;           // row 0..195
        int j = t - r * 36;       // dword col 0..35
        if (j < 35) {
            int Dk = r / 14;
            int m  = r - Dk * 14;
            int gh = h0 + m - 3;
            int gd = d0 + Dk - 3;
            unsigned lo = 0, hi = 0;
            if ((unsigned)gh < 64u && (unsigned)gd < 64u) {
                int rowoff = gd * S2 + gh * S;
                int gw0 = 2 * j - 3;
                int gw1 = gw0 + 1;
                if ((unsigned)gw0 < 64u) {
                    float xv = xc[rowoff + gw0];
                    int   mv = mb[rowoff + gw0];
                    lo = mv ? f2b_bits(xv) : 0u;
                }
                if ((unsigned)gw1 < 64u) {
                    float xv = xc[rowoff + gw1];
                    int   mv = mb[rowoff + gw1];
                    hi = mv ? f2b_bits(xv) : 0u;
                }
            }
            halo[ROWSLOT * r + ((m >> 1) & 3) + j] = lo | (hi << 16);
        }
    }
    __syncthreads();

    const int wq = tid & 7;
    const int hg = (tid >> 3) & 3;
    const int dd = tid >> 5;

    float acc0[8], acc1[8];
    #pragma unroll
    for (int j = 0; j < 8; ++j) { acc0[j] = 0.f; acc1[j] = 0.f; }

    const float* wc = wdw + c * 343;

    for (int kd = 0; kd < 7; ++kd) {
        const int Dk = dd + kd;
        #pragma unroll
        for (int t = 0; t < 8; ++t) {
            const int m  = 2 * hg + t;
            const int rb = ROWSLOT * (14 * Dk + m) + ((m >> 1) & 3) + 4 * wq;
            unsigned dw[7];
            #pragma unroll
            for (int p = 0; p < 7; ++p) dw[p] = halo[rb + p];  // conflict-free
            float in14[14];
            #pragma unroll
            for (int p = 0; p < 7; ++p) {
                in14[2 * p]     = lo2f(dw[p]);
                in14[2 * p + 1] = hi2f(dw[p]);
            }
            if (t <= 6) {                                    // h = 2hg,   kh = t
                const float* wr = wc + kd * 49 + t * 7;
                #pragma unroll
                for (int kw = 0; kw < 7; ++kw) {
                    float wt = wr[kw];
                    #pragma unroll
                    for (int j = 0; j < 8; ++j)
                        acc0[j] = fmaf(wt, in14[j + kw], acc0[j]);
                }
            }
            if (t >= 1) {                                    // h = 2hg+1, kh = t-1
                const float* wr = wc + kd * 49 + (t - 1) * 7;
                #pragma unroll
                for (int kw = 0; kw < 7; ++kw) {
                    float wt = wr[kw];
                    #pragma unroll
                    for (int j = 0; j < 8; ++j)
                        acc1[j] = fmaf(wt, in14[j + kw], acc1[j]);
                }
            }
        }
    }

    const int w0  = wq << 3;
    const int gd  = d0 + dd;
    const int gh0 = h0 + 2 * hg;
    const float bb = bdw[c];
    const size_t obase = (size_t)(b * C + c) * S3 + gd * S2 + gh0 * S + w0;
    const int mbase = gd * S2 + gh0 * S + w0;

    float ov[8];
    #pragma unroll
    for (int j = 0; j < 8; ++j)
        ov[j] = (mb[mbase + j] != 0) ? (acc0[j] + bb) : 0.f;
    *(float4*)(y + obase)     = make_float4(ov[0], ov[1], ov[2], ov[3]);
    *(float4*)(y + obase + 4) = make_float4(ov[4], ov[5], ov[6], ov[7]);

    #pragma unroll
    for (int j = 0; j < 8; ++j)
        ov[j] = (mb[mbase + S + j] != 0) ? (acc1[j] + bb) : 0.f;
    *(float4*)(y + obase + S)     = make_float4(ov[0], ov[1], ov[2], ov[3]);
    *(float4*)(y + obase + S + 4) = make_float4(ov[4], ov[5], ov[6], ov[7]);
}

// ---- sorted compaction over ALL NVOX voxels: count -> scan -> scatter
__global__ __launch_bounds__(256) void k_count(
    const int* __restrict__ mask, int* __restrict__ bcnt)
{
    int v = blockIdx.x * 256 + threadIdx.x;
    int act = (mask[v] != 0) ? 1 : 0;
    unsigned long long ball = __ballot(act);
    __shared__ int wsum[4];
    int lane = threadIdx.x & 63, wid = threadIdx.x >> 6;
    if (lane == 0) wsum[wid] = __popcll(ball);
    __syncthreads();
    if (threadIdx.x == 0)
        bcnt[blockIdx.x] = wsum[0] + wsum[1] + wsum[2] + wsum[3];
}

__global__ __launch_bounds__(256) void k_scan(
    const int* __restrict__ bcnt, int* __restrict__ bbase, int* __restrict__ ntot)
{
    int t = threadIdx.x;                 // 256 threads, 8 counts each (2048 blocks)
    int cv[8]; int s = 0;
    #pragma unroll
    for (int j = 0; j < 8; ++j) { cv[j] = bcnt[t * 8 + j]; s += cv[j]; }
    int lane = t & 63, wid = t >> 6;
    int x = s;                           // inclusive wave scan
    #pragma unroll
    for (int off = 1; off < 64; off <<= 1) {
        int yv = __shfl_up(x, off, 64);
        if (lane >= off) x += yv;
    }
    __shared__ int wtot[4];
    if (lane == 63) wtot[wid] = x;
    __syncthreads();
    int wbase = 0;
    for (int w = 0; w < wid; ++w) wbase += wtot[w];
    int run = wbase + x - s;             // exclusive prefix for this thread's first block
    #pragma unroll
    for (int j = 0; j < 8; ++j) { bbase[t * 8 + j] = run; run += cv[j]; }
    if (t == 255) *ntot = run;
}

__global__ __launch_bounds__(256) void k_scatter(
    const int* __restrict__ mask, const int* __restrict__ bbase,
    int* __restrict__ list)
{
    int v = blockIdx.x * 256 + threadIdx.x;
    int act = (mask[v] != 0) ? 1 : 0;
    unsigned long long ball = __ballot(act);
    int lane = threadIdx.x & 63, wid = threadIdx.x >> 6;
    __shared__ int wcnt[4];
    if (lane == 0) wcnt[wid] = __popcll(ball);
    __syncthreads();
    int base = bbase[blockIdx.x];
    for (int w = 0; w < wid; ++w) base += wcnt[w];
    int pre = __popcll(ball & ((1ull << lane) - 1ull));
    if (act) list[base + pre] = v;       // globally sorted: blocks & lanes in order
}

// Fast erf: Abramowitz-Stegun 7.1.26 (|err| < 2e-6) with HW rcp.
__device__ __forceinline__ float erf_fast(float z) {
    float az = fabsf(z);
    float t = __builtin_amdgcn_rcpf(fmaf(0.3275911f, az, 1.f));
    float p = t * fmaf(t, fmaf(t, fmaf(t, fmaf(t, 1.061405429f, -1.453152027f),
                     1.421413741f), -0.284496736f), 0.254829592f);
    float r = 1.f - p * __expf(-az * az);
    return copysignf(r, z);
}

// Per-active-voxel: LN over C, expand+GELU, project, +residual.
__global__ __launch_bounds__(256) void k_mlp(
    const float* __restrict__ x,
    const float* __restrict__ lng,
    const float* __restrict__ lnb,
    const float* __restrict__ w2,
    const float* __restrict__ b2v,
    const float* __restrict__ w3,
    const float* __restrict__ b3v,
    const int* __restrict__ mask,
    const int* __restrict__ ntot,
    const int* __restrict__ list,
    float* __restrict__ out)
{
    int i = blockIdx.x * 256 + threadIdx.x;
    int v;
    if (list != nullptr) {
        if (i >= *ntot) return;
        v = list[i];                     // sorted -> near-coalesced gathers
    } else {
        v = i;
        if (mask[v] == 0) return;
    }
    const int b = v >> 18;
    const int s = v & (S3 - 1);
    const size_t base = (size_t)b * C * S3 + s;

    float yv[32];
    #pragma unroll
    for (int c = 0; c < 32; ++c) yv[c] = out[base + (size_t)c * S3];

    float mu = 0.f;
    #pragma unroll
    for (int c = 0; c < 32; ++c) mu += yv[c];
    mu *= (1.f / 32.f);
    float var = 0.f;
    #pragma unroll
    for (int c = 0; c < 32; ++c) { float d = yv[c] - mu; var += d * d; }
    var *= (1.f / 32.f);
    const float rs = rsqrtf(var + LN_EPS);
    #pragma unroll
    for (int c = 0; c < 32; ++c)
        yv[c] = (yv[c] - mu) * rs * lng[c] + lnb[c];

    float o[32];
    #pragma unroll
    for (int c = 0; c < 32; ++c) o[c] = b3v[c];

    const float4* w3q = (const float4*)w3;          // w3[c][e]: float4 at c*32 + e/4
    for (int e0 = 0; e0 < E; e0 += 4) {
        float a0 = b2v[e0], a1 = b2v[e0 + 1], a2 = b2v[e0 + 2], a3 = b2v[e0 + 3];
        const float* w2r = w2 + e0 * 32;            // uniform -> scalar loads
        #pragma unroll
        for (int c = 0; c < 32; ++c) {
            float yc = yv[c];
            a0 = fmaf(w2r[c],      yc, a0);
            a1 = fmaf(w2r[32 + c], yc, a1);
            a2 = fmaf(w2r[64 + c], yc, a2);
            a3 = fmaf(w2r[96 + c], yc, a3);
        }
        const float k = 0.70710678118654752f;
        float g0 = 0.5f * a0 * (1.f + erf_fast(a0 * k));
        float g1 = 0.5f * a1 * (1.f + erf_fast(a1 * k));
        float g2 = 0.5f * a2 * (1.f + erf_fast(a2 * k));
        float g3 = 0.5f * a3 * (1.f + erf_fast(a3 * k));
        const int eq = e0 >> 2;
        #pragma unroll
        for (int c = 0; c < 32; ++c) {
            float4 wv = w3q[c * 32 + eq];           // uniform float4
            float oc = o[c];
            oc = fmaf(wv.x, g0, oc);
            oc = fmaf(wv.y, g1, oc);
            oc = fmaf(wv.z, g2, oc);
            oc = fmaf(wv.w, g3, oc);
            o[c] = oc;
        }
    }

    #pragma unroll
    for (int c = 0; c < 32; ++c) {
        float xm = x[base + (size_t)c * S3];
        out[base + (size_t)c * S3] = xm + o[c];
    }
}

extern "C" void kernel_launch(void* const* d_in, const int* in_sizes, int n_in,
                              void* d_out, int out_size, void* d_ws, size_t ws_size,
                              hipStream_t stream)
{
    const float* x   = (const float*)d_in[0];
    const int*   m   = (const int*)d_in[1];
    const float* wdw = (const float*)d_in[2];
    const float* bdw = (const float*)d_in[3];
    const float* lng = (const float*)d_in[4];
    const float* lnb = (const float*)d_in[5];
    const float* w2  = (const float*)d_in[6];
    const float* b2v = (const float*)d_in[7];
    const float* w3  = (const float*)d_in[8];
    const float* b3v = (const float*)d_in[9];
    float* out = (float*)d_out;

    // conv writes full masked y straight into d_out (inactive voxels -> 0,
    // which is also the correct final output there). No d_out memset needed.
    k_conv<<<dim3(64, 64), 256, 0, stream>>>(x, m, wdw, bdw, out);

    // ws layout: [ntot:4][pad][bcnt:8KB][bbase:8KB][list:2MB]
    const size_t need = 256 + 8192 + 8192 + (size_t)NVOX * sizeof(int);
    if (ws_size >= need) {
        int* ntot  = (int*)d_ws;
        int* bcnt  = (int*)((char*)d_ws + 256);
        int* bbase = (int*)((char*)d_ws + 256 + 8192);
        int* list  = (int*)((char*)d_ws + 256 + 16384);
        k_count  <<<2048, 256, 0, stream>>>(m, bcnt);
        k_scan   <<<1,    256, 0, stream>>>(bcnt, bbase, ntot);
        k_scatter<<<2048, 256, 0, stream>>>(m, bbase, list);
        k_mlp<<<2048, 256, 0, stream>>>(x, lng, lnb, w2, b2v, w3, b3v,
                                        m, ntot, list, out);
    } else {
        k_mlp<<<2048, 256, 0, stream>>>(x, lng, lnb, w2, b2v, w3, b3v,
                                        m, nullptr, nullptr, out);
    }
}

// Round 8
// 389.735 us; speedup vs baseline: 1.6739x; 1.1932x over previous
//
#include <hip/hip_runtime.h>

// Problem constants (B=2, C=32, E=128, S=64, K=7, pad=3). All float32 I/O.
#define S 64
#define S2 4096
#define S3 262144
#define NVOX (2 * S3)     // B * S^3 total voxels
#define C 32
#define E 128
#define LN_EPS 1e-6f

typedef short short8 __attribute__((ext_vector_type(8)));
typedef float f32x4  __attribute__((ext_vector_type(4)));

__device__ __forceinline__ unsigned f2b_bits(float f) {
    union { float f; unsigned u; } x; x.f = f;
    unsigned r = x.u + 0x7fffu + ((x.u >> 16) & 1u);   // RNE
    return r >> 16;
}
__device__ __forceinline__ float hi2f(unsigned u) {
    union { unsigned u; float f; } x; x.u = u & 0xffff0000u; return x.f;
}
__device__ __forceinline__ float lo2f(unsigned u) {
    union { unsigned u; float f; } x; x.u = u << 16; return x.f;
}

// ---------------- A-fragment prep: Toeplitz weights in MFMA A-layout -------
// A[m][k] = w[k-m] for k-m in [0,7), else 0.  Lane L holds A[m=L&15][k=8q+j],
// j=0..7 packed as 4 dwords. frag layout: [c][49][lane][4dw] (1KB per frag).
__global__ __launch_bounds__(64) void k_wfrag(
    const float* __restrict__ wdw, unsigned* __restrict__ frag)
{
    const int kdkh = blockIdx.x;     // 49
    const int c    = blockIdx.y;     // 32
    const int L = threadIdx.x;
    const int m = L & 15, q = L >> 4;
    const float* w = wdw + c * 343 + kdkh * 7;
    unsigned dwv[4];
    #pragma unroll
    for (int p = 0; p < 4; ++p) {
        int kw0 = 8 * q + 2 * p - m;
        int kw1 = kw0 + 1;
        unsigned lo = ((unsigned)kw0 < 7u) ? f2b_bits(w[kw0]) : 0u;
        unsigned hi = ((unsigned)kw1 < 7u) ? f2b_bits(w[kw1]) : 0u;
        dwv[p] = lo | (hi << 16);
    }
    *(uint4*)(frag + (c * 49 + kdkh) * 256 + L * 4) =
        make_uint4(dwv[0], dwv[1], dwv[2], dwv[3]);
}

// ---------------- MFMA depthwise conv -------------------------------------
// Block 512 thr = 8 waves = 4 dd-pairs x 2 w-pairs. Tile: d 8, h 16, w 64.
// Halo: 14 slabs x 22 rows x 72 bf16 (36 dw, 16B-aligned rows). Per
// (kh, input-slab): one b128 read feeds up to 4 MFMAs (2 dd x shared w-tile).
// D = A(weights,Toeplitz M=w16) x B(input K=32 window, N=16 h-rows);
// lane: D[w=4q+reg][h=lane&15].
#define HALO_DW 11088      // 14*22*36
__global__ __launch_bounds__(512) void k_conv_mfma(
    const float* __restrict__ x,
    const int* __restrict__ mask,
    const unsigned* __restrict__ frag,
    const float* __restrict__ bdw,
    float* __restrict__ y)
{
    __shared__ uint4 halo4[(HALO_DW + 4) / 4 + 1];
    unsigned* halo = (unsigned*)halo4;

    const int bx = blockIdx.x;        // 32: d-tile(8) x h-tile(4)
    const int by = blockIdx.y;        // 64: b*C + c
    const int b  = by >> 5;
    const int c  = by & 31;
    const int d0 = (bx >> 2) * 8;
    const int h0 = (bx & 3) * 16;
    const int tid = threadIdx.x;

    const float* xc = x + (size_t)(b * C + c) * S3;
    const int* mb = mask + (size_t)b * S3;

    // stage masked bf16 halo (packed pairs), zero-pad at edges
    for (int t = tid; t < HALO_DW; t += 512) {
        int r = t / 36;
        int j = t - r * 36;
        int Dk = r / 22;
        int m  = r - Dk * 22;
        int gd = d0 + Dk - 3, gh = h0 + m - 3;
        unsigned lo = 0, hi = 0;
        if ((unsigned)gd < 64u && (unsigned)gh < 64u) {
            int ro = gd * S2 + gh * S;
            int gw0 = 2 * j - 3;
            int gw1 = gw0 + 1;
            if ((unsigned)gw0 < 64u) {
                float xv = xc[ro + gw0]; int mv = mb[ro + gw0];
                lo = mv ? f2b_bits(xv) : 0u;
            }
            if ((unsigned)gw1 < 64u) {
                float xv = xc[ro + gw1]; int mv = mb[ro + gw1];
                hi = mv ? f2b_bits(xv) : 0u;
            }
        }
        halo[t] = lo | (hi << 16);
    }
    if (tid < 8) halo[HALO_DW + tid] = 0;   // zero tail pad (read x0 by k>=22)
    __syncthreads();

    const int lane = tid & 63;
    const int n = lane & 15, q = lane >> 4;
    const int wv = tid >> 6;                 // 0..7
    const int dd0 = (wv >> 1) * 2;           // {0,2,4,6}
    const int w0a = (wv & 1) * 32, w0b = w0a + 16;

    f32x4 aA0 = {0,0,0,0}, aA1 = {0,0,0,0};  // dd0
    f32x4 aB0 = {0,0,0,0}, aB1 = {0,0,0,0};  // dd0+1

    const unsigned* fb = frag + (c * 49) * 256 + (lane << 2);

    for (int kh = 0; kh < 7; ++kh) {
        short8 wf[7];
        #pragma unroll
        for (int k = 0; k < 7; ++k)
            wf[k] = *(const short8*)(fb + ((k * 7 + kh) << 8));
        #pragma unroll
        for (int i = 0; i < 8; ++i) {        // input slab Dk = dd0 + i
            const int Dk = dd0 + i;
            const int rdw = (Dk * 22 + n + kh) * 36 + (q << 2);
            short8 b0 = *(const short8*)&halo4[(rdw + (w0a >> 1)) >> 2];
            short8 b1 = *(const short8*)&halo4[(rdw + (w0b >> 1)) >> 2];
            if (i <= 6) {                    // kd = i for dd0
                aA0 = __builtin_amdgcn_mfma_f32_16x16x32_bf16(wf[i], b0, aA0, 0, 0, 0);
                aA1 = __builtin_amdgcn_mfma_f32_16x16x32_bf16(wf[i], b1, aA1, 0, 0, 0);
            }
            if (i >= 1) {                    // kd = i-1 for dd0+1
                aB0 = __builtin_amdgcn_mfma_f32_16x16x32_bf16(wf[i-1], b0, aB0, 0, 0, 0);
                aB1 = __builtin_amdgcn_mfma_f32_16x16x32_bf16(wf[i-1], b1, aB1, 0, 0, 0);
            }
        }
    }

    const float bb = bdw[c];
    const int gh = h0 + n;
    #pragma unroll
    for (int s = 0; s < 2; ++s) {
        const int gd = d0 + dd0 + s;
        const size_t ob = (size_t)(b * C + c) * S3 + gd * S2 + gh * S;
        const int mo = gd * S2 + gh * S;
        f32x4 a0 = s == 0 ? aA0 : aB0;
        f32x4 a1 = s == 0 ? aA1 : aB1;
        {
            int wq = w0a + (q << 2);
            int4 mv = *(const int4*)(mb + mo + wq);
            float4 o;
            o.x = mv.x ? a0[0] + bb : 0.f;
            o.y = mv.y ? a0[1] + bb : 0.f;
            o.z = mv.z ? a0[2] + bb : 0.f;
            o.w = mv.w ? a0[3] + bb : 0.f;
            *(float4*)(y + ob + wq) = o;
        }
        {
            int wq = w0b + (q << 2);
            int4 mv = *(const int4*)(mb + mo + wq);
            float4 o;
            o.x = mv.x ? a1[0] + bb : 0.f;
            o.y = mv.y ? a1[1] + bb : 0.f;
            o.z = mv.z ? a1[2] + bb : 0.f;
            o.w = mv.w ? a1[3] + bb : 0.f;
            *(float4*)(y + ob + wq) = o;
        }
    }
}

// ---------------- fallback VALU conv (round-7, proven) --------------------
#define VROWSLOT 40
#define VNROWS  196
#define VHALO_SZ (VROWSLOT * VNROWS)
__global__ __launch_bounds__(256) void k_conv_valu(
    const float* __restrict__ x,
    const int* __restrict__ mask,
    const float* __restrict__ wdw,
    const float* __restrict__ bdw,
    float* __restrict__ y)
{
    __shared__ unsigned halo[VHALO_SZ];
    const int bx = blockIdx.x;
    const int by = blockIdx.y;
    const int b  = by >> 5;
    const int c  = by & 31;
    const int d0 = (bx >> 3) * 8;
    const int h0 = (bx & 7) * 8;
    const int tid = threadIdx.x;
    const float* xc = x + (size_t)(b * C + c) * S3;
    const int* mb = mask + (size_t)b * S3;

    for (int t = tid; t < VNROWS * 36; t += 256) {
        int r = t / 36;
        int j = t - r * 36;
        if (j < 35) {
            int Dk = r / 14;
            int m  = r - Dk * 14;
            int gh = h0 + m - 3;
            int gd = d0 + Dk - 3;
            unsigned lo = 0, hi = 0;
            if ((unsigned)gh < 64u && (unsigned)gd < 64u) {
                int rowoff = gd * S2 + gh * S;
                int gw0 = 2 * j - 3, gw1 = gw0 + 1;
                if ((unsigned)gw0 < 64u) {
                    float xv = xc[rowoff + gw0]; int mv = mb[rowoff + gw0];
                    lo = mv ? f2b_bits(xv) : 0u;
                }
                if ((unsigned)gw1 < 64u) {
                    float xv = xc[rowoff + gw1]; int mv = mb[rowoff + gw1];
                    hi = mv ? f2b_bits(xv) : 0u;
                }
            }
            halo[VROWSLOT * r + ((m >> 1) & 3) + j] = lo | (hi << 16);
        }
    }
    __syncthreads();

    const int wq = tid & 7;
    const int hg = (tid >> 3) & 3;
    const int dd = tid >> 5;
    float acc0[8], acc1[8];
    #pragma unroll
    for (int j = 0; j < 8; ++j) { acc0[j] = 0.f; acc1[j] = 0.f; }
    const float* wc = wdw + c * 343;

    for (int kd = 0; kd < 7; ++kd) {
        const int Dk = dd + kd;
        #pragma unroll
        for (int t = 0; t < 8; ++t) {
            const int m  = 2 * hg + t;
            const int rb = VROWSLOT * (14 * Dk + m) + ((m >> 1) & 3) + 4 * wq;
            unsigned dw[7];
            #pragma unroll
            for (int p = 0; p < 7; ++p) dw[p] = halo[rb + p];
            float in14[14];
            #pragma unroll
            for (int p = 0; p < 7; ++p) {
                in14[2 * p]     = lo2f(dw[p]);
                in14[2 * p + 1] = hi2f(dw[p]);
            }
            if (t <= 6) {
                const float* wr = wc + kd * 49 + t * 7;
                #pragma unroll
                for (int kw = 0; kw < 7; ++kw) {
                    float wt = wr[kw];
                    #pragma unroll
                    for (int j = 0; j < 8; ++j)
                        acc0[j] = fmaf(wt, in14[j + kw], acc0[j]);
                }
            }
            if (t >= 1) {
                const float* wr = wc + kd * 49 + (t - 1) * 7;
                #pragma unroll
                for (int kw = 0; kw < 7; ++kw) {
                    float wt = wr[kw];
                    #pragma unroll
                    for (int j = 0; j < 8; ++j)
                        acc1[j] = fmaf(wt, in14[j + kw], acc1[j]);
                }
            }
        }
    }

    const int w0  = wq << 3;
    const int gd  = d0 + dd;
    const int gh0 = h0 + 2 * hg;
    const float bb = bdw[c];
    const size_t obase = (size_t)(b * C + c) * S3 + gd * S2 + gh0 * S + w0;
    const int mbase = gd * S2 + gh0 * S + w0;
    float ov[8];
    #pragma unroll
    for (int j = 0; j < 8; ++j)
        ov[j] = (mb[mbase + j] != 0) ? (acc0[j] + bb) : 0.f;
    *(float4*)(y + obase)     = make_float4(ov[0], ov[1], ov[2], ov[3]);
    *(float4*)(y + obase + 4) = make_float4(ov[4], ov[5], ov[6], ov[7]);
    #pragma unroll
    for (int j = 0; j < 8; ++j)
        ov[j] = (mb[mbase + S + j] != 0) ? (acc1[j] + bb) : 0.f;
    *(float4*)(y + obase + S)     = make_float4(ov[0], ov[1], ov[2], ov[3]);
    *(float4*)(y + obase + S + 4) = make_float4(ov[4], ov[5], ov[6], ov[7]);
}

// ---- sorted compaction over ALL NVOX voxels: count -> scan -> scatter
__global__ __launch_bounds__(256) void k_count(
    const int* __restrict__ mask, int* __restrict__ bcnt)
{
    int v = blockIdx.x * 256 + threadIdx.x;
    int act = (mask[v] != 0) ? 1 : 0;
    unsigned long long ball = __ballot(act);
    __shared__ int wsum[4];
    int lane = threadIdx.x & 63, wid = threadIdx.x >> 6;
    if (lane == 0) wsum[wid] = __popcll(ball);
    __syncthreads();
    if (threadIdx.x == 0)
        bcnt[blockIdx.x] = wsum[0] + wsum[1] + wsum[2] + wsum[3];
}

__global__ __launch_bounds__(256) void k_scan(
    const int* __restrict__ bcnt, int* __restrict__ bbase, int* __restrict__ ntot)
{
    int t = threadIdx.x;
    int cv[8]; int s = 0;
    #pragma unroll
    for (int j = 0; j < 8; ++j) { cv[j] = bcnt[t * 8 + j]; s += cv[j]; }
    int lane = t & 63, wid = t >> 6;
    int x = s;
    #pragma unroll
    for (int off = 1; off < 64; off <<= 1) {
        int yv = __shfl_up(x, off, 64);
        if (lane >= off) x += yv;
    }
    __shared__ int wtot[4];
    if (lane == 63) wtot[wid] = x;
    __syncthreads();
    int wbase = 0;
    for (int w = 0; w < wid; ++w) wbase += wtot[w];
    int run = wbase + x - s;
    #pragma unroll
    for (int j = 0; j < 8; ++j) { bbase[t * 8 + j] = run; run += cv[j]; }
    if (t == 255) *ntot = run;
}

__global__ __launch_bounds__(256) void k_scatter(
    const int* __restrict__ mask, const int* __restrict__ bbase,
    int* __restrict__ list)
{
    int v = blockIdx.x * 256 + threadIdx.x;
    int act = (mask[v] != 0) ? 1 : 0;
    unsigned long long ball = __ballot(act);
    int lane = threadIdx.x & 63, wid = threadIdx.x >> 6;
    __shared__ int wcnt[4];
    if (lane == 0) wcnt[wid] = __popcll(ball);
    __syncthreads();
    int base = bbase[blockIdx.x];
    for (int w = 0; w < wid; ++w) base += wcnt[w];
    int pre = __popcll(ball & ((1ull << lane) - 1ull));
    if (act) list[base + pre] = v;
}

// Fast erf: Abramowitz-Stegun 7.1.26 (|err| < 2e-6) with HW rcp.
__device__ __forceinline__ float erf_fast(float z) {
    float az = fabsf(z);
    float t = __builtin_amdgcn_rcpf(fmaf(0.3275911f, az, 1.f));
    float p = t * fmaf(t, fmaf(t, fmaf(t, fmaf(t, 1.061405429f, -1.453152027f),
                     1.421413741f), -0.284496736f), 0.254829592f);
    float r = 1.f - p * __expf(-az * az);
    return copysignf(r, z);
}

// Per-active-voxel: LN over C, expand+GELU, project, +residual.
__global__ __launch_bounds__(256) void k_mlp(
    const float* __restrict__ x,
    const float* __restrict__ lng,
    const float* __restrict__ lnb,
    const float* __restrict__ w2,
    const float* __restrict__ b2v,
    const float* __restrict__ w3,
    const float* __restrict__ b3v,
    const int* __restrict__ mask,
    const int* __restrict__ ntot,
    const int* __restrict__ list,
    float* __restrict__ out)
{
    int i = blockIdx.x * 256 + threadIdx.x;
    int v;
    if (list != nullptr) {
        if (i >= *ntot) return;
        v = list[i];
    } else {
        v = i;
        if (mask[v] == 0) return;
    }
    const int b = v >> 18;
    const int s = v & (S3 - 1);
    const size_t base = (size_t)b * C * S3 + s;

    float yv[32];
    #pragma unroll
    for (int c = 0; c < 32; ++c) yv[c] = out[base + (size_t)c * S3];

    float mu = 0.f;
    #pragma unroll
    for (int c = 0; c < 32; ++c) mu += yv[c];
    mu *= (1.f / 32.f);
    float var = 0.f;
    #pragma unroll
    for (int c = 0; c < 32; ++c) { float d = yv[c] - mu; var += d * d; }
    var *= (1.f / 32.f);
    const float rs = rsqrtf(var + LN_EPS);
    #pragma unroll
    for (int c = 0; c < 32; ++c)
        yv[c] = (yv[c] - mu) * rs * lng[c] + lnb[c];

    float o[32];
    #pragma unroll
    for (int c = 0; c < 32; ++c) o[c] = b3v[c];

    const float4* w3q = (const float4*)w3;
    for (int e0 = 0; e0 < E; e0 += 4) {
        float a0 = b2v[e0], a1 = b2v[e0 + 1], a2 = b2v[e0 + 2], a3 = b2v[e0 + 3];
        const float* w2r = w2 + e0 * 32;
        #pragma unroll
        for (int c = 0; c < 32; ++c) {
            float yc = yv[c];
            a0 = fmaf(w2r[c],      yc, a0);
            a1 = fmaf(w2r[32 + c], yc, a1);
            a2 = fmaf(w2r[64 + c], yc, a2);
            a3 = fmaf(w2r[96 + c], yc, a3);
        }
        const float k = 0.70710678118654752f;
        float g0 = 0.5f * a0 * (1.f + erf_fast(a0 * k));
        float g1 = 0.5f * a1 * (1.f + erf_fast(a1 * k));
        float g2 = 0.5f * a2 * (1.f + erf_fast(a2 * k));
        float g3 = 0.5f * a3 * (1.f + erf_fast(a3 * k));
        const int eq = e0 >> 2;
        #pragma unroll
        for (int c = 0; c < 32; ++c) {
            float4 wv = w3q[c * 32 + eq];
            float oc = o[c];
            oc = fmaf(wv.x, g0, oc);
            oc = fmaf(wv.y, g1, oc);
            oc = fmaf(wv.z, g2, oc);
            oc = fmaf(wv.w, g3, oc);
            o[c] = oc;
        }
    }

    #pragma unroll
    for (int c = 0; c < 32; ++c) {
        float xm = x[base + (size_t)c * S3];
        out[base + (size_t)c * S3] = xm + o[c];
    }
}

extern "C" void kernel_launch(void* const* d_in, const int* in_sizes, int n_in,
                              void* d_out, int out_size, void* d_ws, size_t ws_size,
                              hipStream_t stream)
{
    const float* x   = (const float*)d_in[0];
    const int*   m   = (const int*)d_in[1];
    const float* wdw = (const float*)d_in[2];
    const float* bdw = (const float*)d_in[3];
    const float* lng = (const float*)d_in[4];
    const float* lnb = (const float*)d_in[5];
    const float* w2  = (const float*)d_in[6];
    const float* b2v = (const float*)d_in[7];
    const float* w3  = (const float*)d_in[8];
    const float* b3v = (const float*)d_in[9];
    float* out = (float*)d_out;

    // ws layout: [ntot:256][bcnt:8K][bbase:8K][list:2MB][wfrag:1.57MB]
    const size_t off_list = 256 + 8192 + 8192;
    const size_t off_frag = off_list + (size_t)NVOX * sizeof(int);
    const size_t frag_sz  = (size_t)32 * 49 * 1024;
    const size_t need_mfma    = off_frag + frag_sz;
    const size_t need_compact = off_frag;

    if (ws_size >= need_mfma) {
        unsigned* fragbuf = (unsigned*)((char*)d_ws + off_frag);
        k_wfrag<<<dim3(49, 32), 64, 0, stream>>>(wdw, fragbuf);
        k_conv_mfma<<<dim3(32, 64), 512, 0, stream>>>(x, m, fragbuf, bdw, out);
    } else {
        k_conv_valu<<<dim3(64, 64), 256, 0, stream>>>(x, m, wdw, bdw, out);
    }

    if (ws_size >= need_compact) {
        int* ntot  = (int*)d_ws;
        int* bcnt  = (int*)((char*)d_ws + 256);
        int* bbase = (int*)((char*)d_ws + 256 + 8192);
        int* list  = (int*)((char*)d_ws + off_list);
        k_count  <<<2048, 256, 0, stream>>>(m, bcnt);
        k_scan   <<<1,    256, 0, stream>>>(bcnt, bbase, ntot);
        k_scatter<<<2048, 256, 0, stream>>>(m, bbase, list);
        k_mlp<<<2048, 256, 0, stream>>>(x, lng, lnb, w2, b2v, w3, b3v,
                                        m, ntot, list, out);
    } else {
        k_mlp<<<2048, 256, 0, stream>>>(x, lng, lnb, w2, b2v, w3, b3v,
                                        m, nullptr, nullptr, out);
    }
}